// Round 9
// baseline (256.070 us; speedup 1.0000x reference)
//
#include <hip/hip_runtime.h>
#include <math.h>

#define NN 384
#define DD 2
#define TT 128
#define EE 256
#define CHUNKS 16
#define CLEN (TT / CHUNKS)            // 8 steps per chunk
#define PAIRBLOCKS ((NN * NN) / 256)  // 576
#define NPARTIAL (PAIRBLOCKS * CHUNKS)

// ws layout (floats): v0t [T][N][D] | Zs [T][N][D] | partials [NPARTIAL] | cnt
#define WS_V0T 0
#define WS_ZS (TT * NN * DD)
#define WS_PART (2 * TT * NN * DD)
#define WS_CNT (WS_PART + NPARTIAL)
#define WS_FLOATS (WS_CNT + 1)

// ---------------------------------------------------------------------------
// K1: blocks 0..95: transpose v0 (N,D,T)->(T,N,D) with coalesced float4 row
// reads. Blocks 96..98: step-start positions Zs[t][n][d] in exact cumsum
// order, float4 row loads pipelining ahead of the serial fma chain.
// Block 0 zeroes out[0] and the finalize counter (every call: harness
// re-poisons ws before each timed launch, so this must re-run each call).
// ---------------------------------------------------------------------------
__global__ __launch_bounds__(256) void prep_kernel(const float* __restrict__ v0,
                                                   const float* __restrict__ z0,
                                                   const float* __restrict__ t0p,
                                                   const float* __restrict__ tnp,
                                                   float* __restrict__ ws,
                                                   float* __restrict__ out) {
    int bx = blockIdx.x;
    if (bx < 96) {
        if (bx == 0 && threadIdx.x == 0) {
            out[0] = 0.0f;
            reinterpret_cast<unsigned int*>(ws + WS_CNT)[0] = 0u;
        }
        int rl = threadIdx.x >> 5;        // 0..7
        int c  = threadIdx.x & 31;        // 0..31
        int r  = bx * 8 + rl;             // row = n*2+d in [0,768)
        float4 v = *reinterpret_cast<const float4*>(v0 + r * TT + c * 4);
        float* dst = ws + WS_V0T + r;
        dst[(c * 4 + 0) * (NN * DD)] = v.x;
        dst[(c * 4 + 1) * (NN * DD)] = v.y;
        dst[(c * 4 + 2) * (NN * DD)] = v.z;
        dst[(c * 4 + 3) * (NN * DD)] = v.w;
    } else {
        int nd = (bx - 96) * 256 + threadIdx.x;   // [0, 768)
        if (nd < NN * DD) {
            float dt = (tnp[0] - t0p[0]) * (1.0f / TT);
            float z = z0[nd];
            const float4* vrow = reinterpret_cast<const float4*>(v0 + nd * TT);
            float* zs = ws + WS_ZS + nd;
            #pragma unroll 4
            for (int c = 0; c < TT / 4; ++c) {
                float4 v = vrow[c];
                int t = c * 4;
                zs[(t + 0) * (NN * DD)] = z; z = fmaf(v.x, dt, z);
                zs[(t + 1) * (NN * DD)] = z; z = fmaf(v.y, dt, z);
                zs[(t + 2) * (NN * DD)] = z; z = fmaf(v.z, dt, z);
                zs[(t + 3) * (NN * DD)] = z; z = fmaf(v.w, dt, z);
            }
        }
    }
}

// ---------------------------------------------------------------------------
// K2: pair chunks (blocks 0..NPARTIAL-1) + event block (block NPARTIAL).
// 3-pt Gauss-Legendre quadrature, reformulated so all sqrt/rsqrt/div cancels:
// for node t_k = u + h*c_k,  beta - m - t_k^2 = bm0 - c_k*(B2 + c_k*A) with
// bm0 = beta-ss, B2 = 2*b*dt, A = a2*dt^2 (u*h = b*dt, h^2 = a2*dt^2).
// contribution = (5*dt/18) * (E1 + 1.6*E2 + E3); a2->0 limit exact; exponent
// <= beta (Cauchy-Schwarz) so no overflow.
// Finalize is fused via last-block-done: each block writes its partial,
// fences, bumps a counter; the last block re-fences, sums the partials and
// atomically subtracts from out (atomic: can't race the event block's add).
// ---------------------------------------------------------------------------
__global__ __launch_bounds__(256) void pair_event_kernel(const float* __restrict__ ws_ro,
                                                         const float* __restrict__ z0,
                                                         const float* __restrict__ beta,
                                                         const float* __restrict__ data,
                                                         const float* __restrict__ t0p,
                                                         const float* __restrict__ tnp,
                                                         float* __restrict__ partials,
                                                         unsigned int* __restrict__ cnt,
                                                         float* __restrict__ out) {
    const float* v0t = ws_ro + WS_V0T;
    const float* Zs  = ws_ro + WS_ZS;
    int bx = blockIdx.x;

    if (bx == NPARTIAL) {
        // ---- event intensity: one block, one event per thread ----
        int e = threadIdx.x;
        float dt = (tnp[0] - t0p[0]) * (1.0f / TT);
        float fi = data[e * 3 + 0];
        float fj = data[e * 3 + 1];
        float tm = data[e * 3 + 2];
        int i = (int)floorf(fi);
        int j = (int)floorf(fj);
        float idx_f = floorf(tm / dt);
        float idx_cl = (idx_f < (float)TT) ? idx_f : (idx_f - 1.0f);
        int idx = (int)idx_cl;
        float rem = tm - idx_f * dt;              // unclamped idx_f, as in ref

        int bi = (idx * NN + i) * DD, bj = (idx * NN + j) * DD;
        float Zi0 = fmaf(v0t[bi + 0], rem, Zs[bi + 0]);
        float Zi1 = fmaf(v0t[bi + 1], rem, Zs[bi + 1]);
        float Zj0 = fmaf(v0t[bj + 0], rem, Zs[bj + 0]);
        float Zj1 = fmaf(v0t[bj + 1], rem, Zs[bj + 1]);
        float d0 = Zi0 - Zj0, d1 = Zi1 - Zj1;
        float contrib = beta[idx] - (d0 * d0 + d1 * d1);

        #pragma unroll
        for (int off = 32; off > 0; off >>= 1) contrib += __shfl_xor(contrib, off, 64);
        if ((threadIdx.x & 63) == 0) atomicAdd(out, contrib);
        return;
    }

    // ---- non-event integral chunk ----
    int pb = bx % PAIRBLOCKS;
    int c  = bx / PAIRBLOCKS;
    int t0 = c * CLEN;
    int tid = pb * 256 + threadIdx.x;
    int i = tid / NN;                              // wave-uniform (384 = 6*64)
    int j = tid - i * NN;

    float acc = 0.0f;
    float dt = (tnp[0] - t0p[0]) * (1.0f / TT);
    if (j > i) {
        const float C1 = 0.1127016654f;            // 1/2 - sqrt(3/5)/2
        const float C2 = 0.5f;
        const float C3 = 0.8872983346f;            // 1/2 + sqrt(3/5)/2
        float dt2  = dt + dt;
        float dtsq = dt * dt;

        int bi = (t0 * NN + i) * DD, bj = (t0 * NN + j) * DD;
        float2 zsi = *reinterpret_cast<const float2*>(Zs + bi);
        float2 zsj = *reinterpret_cast<const float2*>(Zs + bj);
        float dz0 = zsi.x - zsj.x, dz1 = zsi.y - zsj.y;

        #pragma unroll
        for (int s = 0; s < CLEN; ++s) {
            int t = t0 + s;
            float2 vi = *reinterpret_cast<const float2*>(v0t + (t * NN + i) * DD);
            float2 vj = *reinterpret_cast<const float2*>(v0t + (t * NN + j) * DD);
            float dv0 = vi.x - vj.x, dv1 = vi.y - vj.y;

            float a2 = fmaf(dv0, dv0, dv1 * dv1);
            float b  = fmaf(dz0, dv0, dz1 * dv1);
            float ss = fmaf(dz0, dz0, dz1 * dz1);
            float bm0 = beta[t] - ss;
            float B2 = b * dt2;
            float A  = a2 * dtsq;

            float E1 = __expf(fmaf(-C1, fmaf(C1, A, B2), bm0));
            float E2 = __expf(fmaf(-C2, fmaf(C2, A, B2), bm0));
            float E3 = __expf(fmaf(-C3, fmaf(C3, A, B2), bm0));
            acc = fmaf(1.6f, E2, acc + E1 + E3);

            dz0 = fmaf(dv0, dt, dz0);
            dz1 = fmaf(dv1, dt, dz1);
        }
        acc *= dt * 0.27777777777f;                // 5*dt/18, hoisted
    }

    #pragma unroll
    for (int off = 32; off > 0; off >>= 1) acc += __shfl_xor(acc, off, 64);
    __shared__ float wsum[4];
    __shared__ int is_last;
    if ((threadIdx.x & 63) == 0) wsum[threadIdx.x >> 6] = acc;
    __syncthreads();
    if (threadIdx.x == 0) {
        partials[bx] = wsum[0] + wsum[1] + wsum[2] + wsum[3];
        __threadfence();                           // partial visible before count
        unsigned int old = atomicAdd(cnt, 1u);
        is_last = (old == (unsigned int)(NPARTIAL - 1));
    }
    __syncthreads();

    if (is_last) {
        __threadfence();                           // acquire all partials
        float s = 0.0f;
        for (int k = threadIdx.x; k < NPARTIAL; k += 256) s += partials[k];
        #pragma unroll
        for (int off = 32; off > 0; off >>= 1) s += __shfl_xor(s, off, 64);
        __shared__ float fsum[4];
        if ((threadIdx.x & 63) == 0) fsum[threadIdx.x >> 6] = s;
        __syncthreads();
        if (threadIdx.x == 0)
            atomicAdd(out, -(fsum[0] + fsum[1] + fsum[2] + fsum[3]));
    }
}

// ---------------------------------------------------------------------------
// Fallback path (ws too small): monolithic kernels (libm erff), atomics.
// ---------------------------------------------------------------------------
__global__ void zero_out(float* out) { out[0] = 0.0f; }

__device__ __forceinline__ float2 loadV_nt(const float* __restrict__ v, int t, int n) {
    return make_float2(v[(n * DD + 0) * TT + t], v[(n * DD + 1) * TT + t]);
}

__global__ __launch_bounds__(EE) void event_kernel_fb(const float* __restrict__ data,
                                                      const float* __restrict__ z0,
                                                      const float* __restrict__ v0,
                                                      const float* __restrict__ beta,
                                                      const float* __restrict__ t0p,
                                                      const float* __restrict__ tnp,
                                                      float* __restrict__ out) {
    int e = threadIdx.x;
    float dt = (tnp[0] - t0p[0]) * (1.0f / TT);
    float tm = data[e * 3 + 2];
    int i = (int)floorf(data[e * 3 + 0]);
    int j = (int)floorf(data[e * 3 + 1]);
    float idx_f = floorf(tm / dt);
    float idx_cl = (idx_f < (float)TT) ? idx_f : (idx_f - 1.0f);
    int idx = (int)idx_cl;
    float rem = tm - idx_f * dt;

    const float2* z2 = reinterpret_cast<const float2*>(z0);
    float2 zi = z2[i], zj = z2[j];
    for (int t = 0; t < idx; ++t) {
        float2 vi = loadV_nt(v0, t, i), vj = loadV_nt(v0, t, j);
        zi.x = fmaf(vi.x, dt, zi.x); zi.y = fmaf(vi.y, dt, zi.y);
        zj.x = fmaf(vj.x, dt, zj.x); zj.y = fmaf(vj.y, dt, zj.y);
    }
    float2 vi = loadV_nt(v0, idx, i), vj = loadV_nt(v0, idx, j);
    float d0 = fmaf(vi.x, rem, zi.x) - fmaf(vj.x, rem, zj.x);
    float d1 = fmaf(vi.y, rem, zi.y) - fmaf(vj.y, rem, zj.y);
    float contrib = beta[idx] - (d0 * d0 + d1 * d1);
    #pragma unroll
    for (int off = 32; off > 0; off >>= 1) contrib += __shfl_xor(contrib, off, 64);
    if ((threadIdx.x & 63) == 0) atomicAdd(out, contrib);
}

__global__ __launch_bounds__(256) void pair_kernel_fb(const float* __restrict__ v0,
                                                      const float* __restrict__ z0,
                                                      const float* __restrict__ beta,
                                                      const float* __restrict__ t0p,
                                                      const float* __restrict__ tnp,
                                                      float* __restrict__ out) {
    int tid = blockIdx.x * 256 + threadIdx.x;
    int i = tid / NN, j = tid - i * NN;
    float acc = 0.0f;
    if (j > i) {
        float dt = (tnp[0] - t0p[0]) * (1.0f / TT);
        const float2* z2 = reinterpret_cast<const float2*>(z0);
        float2 zi = z2[i], zj = z2[j];
        const float sp_half = 0.8862269254527580f;
        for (int t = 0; t < TT; ++t) {
            float2 vi = loadV_nt(v0, t, i), vj = loadV_nt(v0, t, j);
            float dz0 = zi.x - zj.x, dz1 = zi.y - zj.y;
            float dv0 = vi.x - vj.x, dv1 = vi.y - vj.y;
            float a2 = fmaxf(fmaf(dv0, dv0, dv1 * dv1), 1e-12f);
            float inv_a = rsqrtf(a2);
            float a = a2 * inv_a;
            float b = fmaf(dz0, dv0, dz1 * dv1);
            float u = b * inv_a;
            float m = fmaf(-u, u, fmaf(dz0, dz0, dz1 * dz1));
            float ediff = erff(fmaf(a, dt, u)) - erff(u);
            acc = fmaf(__expf(beta[t] - m) * inv_a, sp_half * ediff, acc);
            zi.x = fmaf(vi.x, dt, zi.x); zi.y = fmaf(vi.y, dt, zi.y);
            zj.x = fmaf(vj.x, dt, zj.x); zj.y = fmaf(vj.y, dt, zj.y);
        }
    }
    #pragma unroll
    for (int off = 32; off > 0; off >>= 1) acc += __shfl_xor(acc, off, 64);
    if ((threadIdx.x & 63) == 0) atomicAdd(out, -acc);
}

// ---------------------------------------------------------------------------
extern "C" void kernel_launch(void* const* d_in, const int* in_sizes, int n_in,
                              void* d_out, int out_size, void* d_ws, size_t ws_size,
                              hipStream_t stream) {
    const float* data = (const float*)d_in[0];
    const float* t0p  = (const float*)d_in[1];
    const float* tnp  = (const float*)d_in[2];
    const float* z0   = (const float*)d_in[3];
    const float* v0   = (const float*)d_in[4];
    const float* beta = (const float*)d_in[5];
    float* out = (float*)d_out;
    float* ws  = (float*)d_ws;

    if (ws_size >= sizeof(float) * (size_t)WS_FLOATS) {
        prep_kernel<<<99, 256, 0, stream>>>(v0, z0, t0p, tnp, ws, out);
        pair_event_kernel<<<NPARTIAL + 1, 256, 0, stream>>>(
            ws, z0, beta, data, t0p, tnp, ws + WS_PART,
            reinterpret_cast<unsigned int*>(ws + WS_CNT), out);
    } else {
        zero_out<<<1, 1, 0, stream>>>(out);
        event_kernel_fb<<<1, EE, 0, stream>>>(data, z0, v0, beta, t0p, tnp, out);
        pair_kernel_fb<<<PAIRBLOCKS, 256, 0, stream>>>(v0, z0, beta, t0p, tnp, out);
    }
}

// Round 11
// 86.409 us; speedup vs baseline: 2.9635x; 2.9635x over previous
//
#include <hip/hip_runtime.h>
#include <math.h>

#define NN 384
#define DD 2
#define TT 128
#define EE 256
#define CHUNKS 16
#define CLEN (TT / CHUNKS)            // 8 steps per chunk
#define PAIRBLOCKS ((NN * NN) / 256)  // 576
#define NPARTIAL (PAIRBLOCKS * CHUNKS)

// ws layout (floats): v0t [T][N][D] | Zs [T][N][D] | partials [NPARTIAL]
#define WS_V0T 0
#define WS_ZS (TT * NN * DD)
#define WS_PART (2 * TT * NN * DD)
#define WS_FLOATS (WS_PART + NPARTIAL)

// NOTE (round-9 lesson, journaled): do NOT fuse the finalize via
// last-block-done + __threadfence(). On gfx950 the per-XCD L2s are
// non-coherent; device-scope fences compile to L2 writeback/invalidate and
// 2 fences x 9216 blocks cost ~190us (vs ~2us for the extra launch).

// ---------------------------------------------------------------------------
// K1: blocks 0..95: transpose v0 (N,D,T)->(T,N,D) with coalesced float4 row
// reads. Blocks 96..98: step-start positions Zs[t][n][d] in exact cumsum
// order, float4 row loads pipelining ahead of the serial fma chain. Zeroes out.
// ---------------------------------------------------------------------------
__global__ __launch_bounds__(256) void prep_kernel(const float* __restrict__ v0,
                                                   const float* __restrict__ z0,
                                                   const float* __restrict__ t0p,
                                                   const float* __restrict__ tnp,
                                                   float* __restrict__ ws,
                                                   float* __restrict__ out) {
    int bx = blockIdx.x;
    if (bx < 96) {
        if (bx == 0 && threadIdx.x == 0) out[0] = 0.0f;
        int rl = threadIdx.x >> 5;        // 0..7
        int c  = threadIdx.x & 31;        // 0..31
        int r  = bx * 8 + rl;             // row = n*2+d in [0,768)
        float4 v = *reinterpret_cast<const float4*>(v0 + r * TT + c * 4);
        float* dst = ws + WS_V0T + r;
        dst[(c * 4 + 0) * (NN * DD)] = v.x;
        dst[(c * 4 + 1) * (NN * DD)] = v.y;
        dst[(c * 4 + 2) * (NN * DD)] = v.z;
        dst[(c * 4 + 3) * (NN * DD)] = v.w;
    } else {
        int nd = (bx - 96) * 256 + threadIdx.x;   // [0, 768)
        if (nd < NN * DD) {
            float dt = (tnp[0] - t0p[0]) * (1.0f / TT);
            float z = z0[nd];
            const float4* vrow = reinterpret_cast<const float4*>(v0 + nd * TT);
            float* zs = ws + WS_ZS + nd;
            #pragma unroll 4
            for (int c = 0; c < TT / 4; ++c) {
                float4 v = vrow[c];
                int t = c * 4;
                zs[(t + 0) * (NN * DD)] = z; z = fmaf(v.x, dt, z);
                zs[(t + 1) * (NN * DD)] = z; z = fmaf(v.y, dt, z);
                zs[(t + 2) * (NN * DD)] = z; z = fmaf(v.z, dt, z);
                zs[(t + 3) * (NN * DD)] = z; z = fmaf(v.w, dt, z);
            }
        }
    }
}

// ---------------------------------------------------------------------------
// K2: pair chunks (blocks 0..NPARTIAL-1) + event block (block NPARTIAL).
// 3-pt Gauss-Legendre quadrature, reformulated so all sqrt/rsqrt/div cancels:
// for node t_k = u + h*c_k,  beta - m - t_k^2 = bm0 - c_k*(B2 + c_k*A) with
// bm0 = beta-ss, B2 = 2*b*dt, A = a2*dt^2 (u*h = b*dt, h^2 = a2*dt^2).
// contribution = (5*dt/18) * (E1 + 1.6*E2 + E3); a2->0 limit exact; exponent
// <= beta (Cauchy-Schwarz) so no overflow.
// ---------------------------------------------------------------------------
__global__ __launch_bounds__(256) void pair_event_kernel(const float* __restrict__ ws_ro,
                                                         const float* __restrict__ z0,
                                                         const float* __restrict__ beta,
                                                         const float* __restrict__ data,
                                                         const float* __restrict__ t0p,
                                                         const float* __restrict__ tnp,
                                                         float* __restrict__ partials,
                                                         float* __restrict__ out) {
    const float* v0t = ws_ro + WS_V0T;
    const float* Zs  = ws_ro + WS_ZS;
    int bx = blockIdx.x;

    if (bx == NPARTIAL) {
        // ---- event intensity: one block, one event per thread ----
        int e = threadIdx.x;
        float dt = (tnp[0] - t0p[0]) * (1.0f / TT);
        float fi = data[e * 3 + 0];
        float fj = data[e * 3 + 1];
        float tm = data[e * 3 + 2];
        int i = (int)floorf(fi);
        int j = (int)floorf(fj);
        float idx_f = floorf(tm / dt);
        float idx_cl = (idx_f < (float)TT) ? idx_f : (idx_f - 1.0f);
        int idx = (int)idx_cl;
        float rem = tm - idx_f * dt;              // unclamped idx_f, as in ref

        int bi = (idx * NN + i) * DD, bj = (idx * NN + j) * DD;
        float Zi0 = fmaf(v0t[bi + 0], rem, Zs[bi + 0]);
        float Zi1 = fmaf(v0t[bi + 1], rem, Zs[bi + 1]);
        float Zj0 = fmaf(v0t[bj + 0], rem, Zs[bj + 0]);
        float Zj1 = fmaf(v0t[bj + 1], rem, Zs[bj + 1]);
        float d0 = Zi0 - Zj0, d1 = Zi1 - Zj1;
        float contrib = beta[idx] - (d0 * d0 + d1 * d1);

        #pragma unroll
        for (int off = 32; off > 0; off >>= 1) contrib += __shfl_xor(contrib, off, 64);
        if ((threadIdx.x & 63) == 0) atomicAdd(out, contrib);
        return;
    }

    // ---- non-event integral chunk ----
    int pb = bx % PAIRBLOCKS;
    int c  = bx / PAIRBLOCKS;
    int t0 = c * CLEN;
    int tid = pb * 256 + threadIdx.x;
    int i = tid / NN;                              // wave-uniform (384 = 6*64)
    int j = tid - i * NN;

    float acc = 0.0f;
    float dt = (tnp[0] - t0p[0]) * (1.0f / TT);
    if (j > i) {
        const float C1 = 0.1127016654f;            // 1/2 - sqrt(3/5)/2
        const float C2 = 0.5f;
        const float C3 = 0.8872983346f;            // 1/2 + sqrt(3/5)/2
        float dt2  = dt + dt;
        float dtsq = dt * dt;

        int bi = (t0 * NN + i) * DD, bj = (t0 * NN + j) * DD;
        float2 zsi = *reinterpret_cast<const float2*>(Zs + bi);
        float2 zsj = *reinterpret_cast<const float2*>(Zs + bj);
        float dz0 = zsi.x - zsj.x, dz1 = zsi.y - zsj.y;

        #pragma unroll
        for (int s = 0; s < CLEN; ++s) {
            int t = t0 + s;
            float2 vi = *reinterpret_cast<const float2*>(v0t + (t * NN + i) * DD);
            float2 vj = *reinterpret_cast<const float2*>(v0t + (t * NN + j) * DD);
            float dv0 = vi.x - vj.x, dv1 = vi.y - vj.y;

            float a2 = fmaf(dv0, dv0, dv1 * dv1);
            float b  = fmaf(dz0, dv0, dz1 * dv1);
            float ss = fmaf(dz0, dz0, dz1 * dz1);
            float bm0 = beta[t] - ss;
            float B2 = b * dt2;
            float A  = a2 * dtsq;

            float E1 = __expf(fmaf(-C1, fmaf(C1, A, B2), bm0));
            float E2 = __expf(fmaf(-C2, fmaf(C2, A, B2), bm0));
            float E3 = __expf(fmaf(-C3, fmaf(C3, A, B2), bm0));
            acc = fmaf(1.6f, E2, acc + E1 + E3);

            dz0 = fmaf(dv0, dt, dz0);
            dz1 = fmaf(dv1, dt, dz1);
        }
        acc *= dt * 0.27777777777f;                // 5*dt/18, hoisted
    }

    #pragma unroll
    for (int off = 32; off > 0; off >>= 1) acc += __shfl_xor(acc, off, 64);
    __shared__ float wsum[4];
    if ((threadIdx.x & 63) == 0) wsum[threadIdx.x >> 6] = acc;
    __syncthreads();
    if (threadIdx.x == 0)
        partials[bx] = wsum[0] + wsum[1] + wsum[2] + wsum[3];
}

// ---------------------------------------------------------------------------
// K3: sum the per-block partials, subtract from out (events already added).
// ---------------------------------------------------------------------------
__global__ __launch_bounds__(1024) void finalize_kernel(const float* __restrict__ partials,
                                                        float* __restrict__ out) {
    float s = 0.0f;
    for (int k = threadIdx.x; k < NPARTIAL; k += 1024) s += partials[k];   // 9 iters
    #pragma unroll
    for (int off = 32; off > 0; off >>= 1) s += __shfl_xor(s, off, 64);
    __shared__ float wsum[16];
    if ((threadIdx.x & 63) == 0) wsum[threadIdx.x >> 6] = s;
    __syncthreads();
    if (threadIdx.x == 0) {
        float tot = 0.0f;
        #pragma unroll
        for (int k = 0; k < 16; ++k) tot += wsum[k];
        out[0] -= tot;
    }
}

// ---------------------------------------------------------------------------
// Fallback path (ws too small): monolithic kernels (libm erff), atomics.
// ---------------------------------------------------------------------------
__global__ void zero_out(float* out) { out[0] = 0.0f; }

__device__ __forceinline__ float2 loadV_nt(const float* __restrict__ v, int t, int n) {
    return make_float2(v[(n * DD + 0) * TT + t], v[(n * DD + 1) * TT + t]);
}

__global__ __launch_bounds__(EE) void event_kernel_fb(const float* __restrict__ data,
                                                      const float* __restrict__ z0,
                                                      const float* __restrict__ v0,
                                                      const float* __restrict__ beta,
                                                      const float* __restrict__ t0p,
                                                      const float* __restrict__ tnp,
                                                      float* __restrict__ out) {
    int e = threadIdx.x;
    float dt = (tnp[0] - t0p[0]) * (1.0f / TT);
    float tm = data[e * 3 + 2];
    int i = (int)floorf(data[e * 3 + 0]);
    int j = (int)floorf(data[e * 3 + 1]);
    float idx_f = floorf(tm / dt);
    float idx_cl = (idx_f < (float)TT) ? idx_f : (idx_f - 1.0f);
    int idx = (int)idx_cl;
    float rem = tm - idx_f * dt;

    const float2* z2 = reinterpret_cast<const float2*>(z0);
    float2 zi = z2[i], zj = z2[j];
    for (int t = 0; t < idx; ++t) {
        float2 vi = loadV_nt(v0, t, i), vj = loadV_nt(v0, t, j);
        zi.x = fmaf(vi.x, dt, zi.x); zi.y = fmaf(vi.y, dt, zi.y);
        zj.x = fmaf(vj.x, dt, zj.x); zj.y = fmaf(vj.y, dt, zj.y);
    }
    float2 vi = loadV_nt(v0, idx, i), vj = loadV_nt(v0, idx, j);
    float d0 = fmaf(vi.x, rem, zi.x) - fmaf(vj.x, rem, zj.x);
    float d1 = fmaf(vi.y, rem, zi.y) - fmaf(vj.y, rem, zj.y);
    float contrib = beta[idx] - (d0 * d0 + d1 * d1);
    #pragma unroll
    for (int off = 32; off > 0; off >>= 1) contrib += __shfl_xor(contrib, off, 64);
    if ((threadIdx.x & 63) == 0) atomicAdd(out, contrib);
}

__global__ __launch_bounds__(256) void pair_kernel_fb(const float* __restrict__ v0,
                                                      const float* __restrict__ z0,
                                                      const float* __restrict__ beta,
                                                      const float* __restrict__ t0p,
                                                      const float* __restrict__ tnp,
                                                      float* __restrict__ out) {
    int tid = blockIdx.x * 256 + threadIdx.x;
    int i = tid / NN, j = tid - i * NN;
    float acc = 0.0f;
    if (j > i) {
        float dt = (tnp[0] - t0p[0]) * (1.0f / TT);
        const float2* z2 = reinterpret_cast<const float2*>(z0);
        float2 zi = z2[i], zj = z2[j];
        const float sp_half = 0.8862269254527580f;
        for (int t = 0; t < TT; ++t) {
            float2 vi = loadV_nt(v0, t, i), vj = loadV_nt(v0, t, j);
            float dz0 = zi.x - zj.x, dz1 = zi.y - zj.y;
            float dv0 = vi.x - vj.x, dv1 = vi.y - vj.y;
            float a2 = fmaxf(fmaf(dv0, dv0, dv1 * dv1), 1e-12f);
            float inv_a = rsqrtf(a2);
            float a = a2 * inv_a;
            float b = fmaf(dz0, dv0, dz1 * dv1);
            float u = b * inv_a;
            float m = fmaf(-u, u, fmaf(dz0, dz0, dz1 * dz1));
            float ediff = erff(fmaf(a, dt, u)) - erff(u);
            acc = fmaf(__expf(beta[t] - m) * inv_a, sp_half * ediff, acc);
            zi.x = fmaf(vi.x, dt, zi.x); zi.y = fmaf(vi.y, dt, zi.y);
            zj.x = fmaf(vj.x, dt, zj.x); zj.y = fmaf(vj.y, dt, zj.y);
        }
    }
    #pragma unroll
    for (int off = 32; off > 0; off >>= 1) acc += __shfl_xor(acc, off, 64);
    if ((threadIdx.x & 63) == 0) atomicAdd(out, -acc);
}

// ---------------------------------------------------------------------------
extern "C" void kernel_launch(void* const* d_in, const int* in_sizes, int n_in,
                              void* d_out, int out_size, void* d_ws, size_t ws_size,
                              hipStream_t stream) {
    const float* data = (const float*)d_in[0];
    const float* t0p  = (const float*)d_in[1];
    const float* tnp  = (const float*)d_in[2];
    const float* z0   = (const float*)d_in[3];
    const float* v0   = (const float*)d_in[4];
    const float* beta = (const float*)d_in[5];
    float* out = (float*)d_out;
    float* ws  = (float*)d_ws;

    if (ws_size >= sizeof(float) * (size_t)WS_FLOATS) {
        prep_kernel<<<99, 256, 0, stream>>>(v0, z0, t0p, tnp, ws, out);
        pair_event_kernel<<<NPARTIAL + 1, 256, 0, stream>>>(ws, z0, beta, data, t0p, tnp,
                                                            ws + WS_PART, out);
        finalize_kernel<<<1, 1024, 0, stream>>>(ws + WS_PART, out);
    } else {
        zero_out<<<1, 1, 0, stream>>>(out);
        event_kernel_fb<<<1, EE, 0, stream>>>(data, z0, v0, beta, t0p, tnp, out);
        pair_kernel_fb<<<PAIRBLOCKS, 256, 0, stream>>>(v0, z0, beta, t0p, tnp, out);
    }
}